// Round 1
// baseline (450.012 us; speedup 1.0000x reference)
//
#include <hip/hip_runtime.h>
#include <hip/hip_bf16.h>

// Problem constants
#define V_   16000
#define D_   1024
#define H_   1024
#define E_   8
#define C_   16
#define B_   64
#define S_   512
#define GH_  256
#define NPAIR 128   // B_ * K(=2)

typedef short  bf16x8 __attribute__((ext_vector_type(8)));
typedef ushort u16x8  __attribute__((ext_vector_type(8)));
typedef float  f32x4  __attribute__((ext_vector_type(4)));

static __device__ __forceinline__ ushort f2bf(float f) {
  union { float f; unsigned u; } un; un.f = f;
  unsigned u = un.u;
  return (ushort)((u + 0x7FFFu + ((u >> 16) & 1u)) >> 16);  // RNE
}

// ---------------------------------------------------------------------------
// Kernel 0: transpose+convert exp_w1 (E,D,H) f32 -> w1t (E,H,D) bf16
// grid (D/64, H/64, E), block 256
__global__ void w1_transpose_kernel(const float* __restrict__ w1,
                                    ushort* __restrict__ w1t) {
  __shared__ float tile[64][65];
  const int d0 = blockIdx.x * 64, h0 = blockIdx.y * 64, e = blockIdx.z;
  const float* src = w1 + (size_t)e * D_ * H_;
  for (int i = threadIdx.x; i < 64 * 64; i += 256) {
    int r = i >> 6, c = i & 63;                 // r: d, c: h
    tile[r][c] = src[(size_t)(d0 + r) * H_ + h0 + c];
  }
  __syncthreads();
  ushort* dst = w1t + (size_t)e * H_ * D_;
  for (int i = threadIdx.x; i < 64 * 64; i += 256) {
    int r = i >> 6, c = i & 63;                 // r: h, c: d
    dst[(size_t)(h0 + r) * D_ + d0 + c] = f2bf(tile[c][r]);
  }
}

// ---------------------------------------------------------------------------
// Kernel 1: pooled[b][d] = mean_s emb[x[b,s]][d]   grid(64), block 256 (float4)
__global__ void pool_kernel(const int* __restrict__ x,
                            const float* __restrict__ emb,
                            float* __restrict__ pooled) {
  const int b = blockIdx.x, t = threadIdx.x;
  const int* xr = x + b * S_;
  float4 acc = make_float4(0.f, 0.f, 0.f, 0.f);
  #pragma unroll 4
  for (int s = 0; s < S_; ++s) {
    const float4* row = reinterpret_cast<const float4*>(emb + (size_t)xr[s] * D_);
    float4 v = row[t];
    acc.x += v.x; acc.y += v.y; acc.z += v.z; acc.w += v.w;
  }
  const float inv = 1.f / (float)S_;
  float4 o = make_float4(acc.x * inv, acc.y * inv, acc.z * inv, acc.w * inv);
  reinterpret_cast<float4*>(pooled + (size_t)b * D_)[t] = o;
}

// ---------------------------------------------------------------------------
// Kernel 2: gating MLP + top-2 + renormalize (all f32 - controls routing)
// grid(64), block 256 (one thread per hidden unit)
__global__ void gate_kernel(const float* __restrict__ pooled,
                            const float* __restrict__ gw1, const float* __restrict__ gb1,
                            const float* __restrict__ gw2, const float* __restrict__ gb2,
                            int* __restrict__ ridx, float* __restrict__ rwgt) {
  const int b = blockIdx.x, j = threadIdx.x;
  __shared__ float hid[GH_];
  __shared__ float logits[E_];
  float acc = gb1[j];
  const float* pb = pooled + (size_t)b * D_;
  for (int d = 0; d < D_; ++d) acc += pb[d] * gw1[d * GH_ + j];
  hid[j] = fmaxf(acc, 0.f);
  __syncthreads();
  if (j < E_) {
    float l = gb2[j];
    for (int i = 0; i < GH_; ++i) l += hid[i] * gw2[i * E_ + j];
    logits[j] = l;
  }
  __syncthreads();
  if (j == 0) {
    // top-1 (ascending scan, strict > keeps lowest index on ties - matches lax.top_k)
    int i0 = 0; float v0 = logits[0];
    for (int i = 1; i < E_; ++i) if (logits[i] > v0) { v0 = logits[i]; i0 = i; }
    int i1 = -1; float v1 = -3.0e38f;
    for (int i = 0; i < E_; ++i) {
      if (i == i0) continue;
      if (logits[i] > v1) { v1 = logits[i]; i1 = i; }
    }
    // renormalized top-2 softmax == softmax over the two logits (denominators cancel)
    float r1 = expf(v1 - v0);
    float norm = 1.f + r1;
    ridx[b * 2 + 0] = i0;        ridx[b * 2 + 1] = i1;
    rwgt[b * 2 + 0] = 1.f / norm; rwgt[b * 2 + 1] = r1 / norm;
  }
}

// ---------------------------------------------------------------------------
// Kernel 3: per-pair gathered GEMM + bias + ReLU + sum over s
// D-tile roles: A = w1t (r=h, k-contig), B = tok (c=s, k-contig)
// block tile: BH=128 h x BS=64 s, BK=64; grid (S/BS=8, H/BH=8, NPAIR=128)
#define BH 128
#define BS 64
#define BK 64
#define LDA 72   // 64 + 8 pad (bf16 elems) -> 144B row stride, 16B aligned
#define LDB 72

__global__ __launch_bounds__(256) void expert_kernel(
    const int* __restrict__ x, const float* __restrict__ exp_emb,
    const ushort* __restrict__ w1t, const float* __restrict__ exp_b1,
    const int* __restrict__ ridx, float* __restrict__ p_part) {
  const int sblk = blockIdx.x;   // 0..7
  const int hblk = blockIdx.y;   // 0..7
  const int pr   = blockIdx.z;   // 0..127
  const int b    = pr >> 1;
  const int tid  = threadIdx.x;

  __shared__ __align__(16) ushort lA[BH * LDA];
  __shared__ __align__(16) ushort lB[BS * LDB];
  __shared__ unsigned tokOff[BS];
  __shared__ float sB1[BH];

  const int e     = ridx[pr];
  const int hBase = hblk * BH;
  const int sBase = sblk * BS;

  if (tid < BS) {
    int token = x[b * S_ + sBase + tid];
    tokOff[tid] = (unsigned)(e * V_ + token) * (unsigned)D_;
  }
  if (tid < BH) sB1[tid] = exp_b1[e * H_ + hBase + tid];
  __syncthreads();

  const ushort* w1tBase = w1t + (size_t)(e * H_ + hBase) * D_;

  const int wid = tid >> 6, lane = tid & 63;
  const int l15 = lane & 15, l16 = lane >> 4;
  const int wh  = wid * 32;               // wave owns h rows [wh, wh+32)

  f32x4 acc[2][4];
  #pragma unroll
  for (int i = 0; i < 2; ++i)
    #pragma unroll
    for (int j = 0; j < 4; ++j) acc[i][j] = (f32x4){0.f, 0.f, 0.f, 0.f};

  const int arow = tid >> 1, acol = (tid & 1) * 32;  // A: 32 bf16/thread
  const int brow = tid >> 2, bq   = (tid & 3) * 16;  // B: 16 f32/thread
  const float* tokBase = exp_emb + tokOff[brow];

  for (int kb = 0; kb < D_; kb += BK) {
    // stage A: 128 x 64 bf16 from w1t (already bf16, contiguous)
    {
      const u16x8* src = reinterpret_cast<const u16x8*>(w1tBase + (size_t)arow * D_ + kb + acol);
      u16x8 a0 = src[0], a1 = src[1], a2 = src[2], a3 = src[3];
      u16x8* dst = reinterpret_cast<u16x8*>(&lA[arow * LDA + acol]);
      dst[0] = a0; dst[1] = a1; dst[2] = a2; dst[3] = a3;
    }
    // stage B: gather 64 token rows x 64 f32, convert -> bf16
    {
      const float4* src = reinterpret_cast<const float4*>(tokBase + kb + bq);
      float4 f0 = src[0], f1 = src[1], f2 = src[2], f3 = src[3];
      u16x8 v0, v1;
      v0[0]=f2bf(f0.x); v0[1]=f2bf(f0.y); v0[2]=f2bf(f0.z); v0[3]=f2bf(f0.w);
      v0[4]=f2bf(f1.x); v0[5]=f2bf(f1.y); v0[6]=f2bf(f1.z); v0[7]=f2bf(f1.w);
      v1[0]=f2bf(f2.x); v1[1]=f2bf(f2.y); v1[2]=f2bf(f2.z); v1[3]=f2bf(f2.w);
      v1[4]=f2bf(f3.x); v1[5]=f2bf(f3.y); v1[6]=f2bf(f3.z); v1[7]=f2bf(f3.w);
      u16x8* dst = reinterpret_cast<u16x8*>(&lB[brow * LDB + bq]);
      dst[0] = v0; dst[1] = v1;
    }
    __syncthreads();

    #pragma unroll
    for (int ks = 0; ks < 2; ++ks) {
      const int koff = ks * 32 + l16 * 8;
      bf16x8 af[2], bfr[4];
      #pragma unroll
      for (int i = 0; i < 2; ++i)
        af[i] = *reinterpret_cast<const bf16x8*>(&lA[(wh + i * 16 + l15) * LDA + koff]);
      #pragma unroll
      for (int j = 0; j < 4; ++j)
        bfr[j] = *reinterpret_cast<const bf16x8*>(&lB[(j * 16 + l15) * LDB + koff]);
      #pragma unroll
      for (int i = 0; i < 2; ++i)
        #pragma unroll
        for (int j = 0; j < 4; ++j)
          acc[i][j] = __builtin_amdgcn_mfma_f32_16x16x32_bf16(af[i], bfr[j], acc[i][j], 0, 0, 0);
    }
    __syncthreads();
  }

  // epilogue: + bias, ReLU, sum over the 64 s columns, store partial
  float* outRow = p_part + (size_t)(sblk * NPAIR + pr) * H_ + hBase;
  #pragma unroll
  for (int i = 0; i < 2; ++i) {
    #pragma unroll
    for (int r = 0; r < 4; ++r) {
      const int hloc = wh + i * 16 + l16 * 4 + r;   // D row = (lane>>4)*4 + reg
      const float bias = sB1[hloc];
      float v = 0.f;
      #pragma unroll
      for (int j = 0; j < 4; ++j) v += fmaxf(acc[i][j][r] + bias, 0.f);
      #pragma unroll
      for (int m = 1; m < 16; m <<= 1) v += __shfl_xor(v, m);  // reduce 16 s-cols
      if (l15 == 0) outRow[hloc] = v;
    }
  }
}

// ---------------------------------------------------------------------------
// Kernel 4: out[b][c] = sum_k rw * ( (sum_sb p_part)/S @ W2[e] + b2[e] )
// grid(64), block 256: c = t&15, group g = t>>4
__global__ void finalize_kernel(const float* __restrict__ p_part,
                                const int* __restrict__ ridx, const float* __restrict__ rwgt,
                                const float* __restrict__ w2, const float* __restrict__ b2,
                                float* __restrict__ out) {
  const int b = blockIdx.x, t = threadIdx.x;
  const int c = t & 15, g = t >> 4;
  __shared__ float red[16][17];
  float res = 0.f;
  for (int kk = 0; kk < 2; ++kk) {
    const int pr = b * 2 + kk;
    const int e = ridx[pr];
    const float w = rwgt[pr];
    float dot = 0.f;
    for (int h = g; h < H_; h += 16) {
      float pm = 0.f;
      #pragma unroll
      for (int sb = 0; sb < 8; ++sb) pm += p_part[(size_t)(sb * NPAIR + pr) * H_ + h];
      dot += pm * w2[((size_t)e * H_ + h) * C_ + c];
    }
    red[g][c] = dot;
    __syncthreads();
    if (g == 0) {
      float s = 0.f;
      #pragma unroll
      for (int i = 0; i < 16; ++i) s += red[i][c];
      res += w * (s * (1.f / (float)S_) + b2[e * C_ + c]);
    }
    __syncthreads();
  }
  if (g == 0) out[b * C_ + c] = res;
}

// ---------------------------------------------------------------------------
extern "C" void kernel_launch(void* const* d_in, const int* in_sizes, int n_in,
                              void* d_out, int out_size, void* d_ws, size_t ws_size,
                              hipStream_t stream) {
  const int*   x    = (const int*)  d_in[0];
  const float* emb  = (const float*)d_in[1];
  const float* gw1  = (const float*)d_in[2];
  const float* gb1  = (const float*)d_in[3];
  const float* gw2  = (const float*)d_in[4];
  const float* gb2  = (const float*)d_in[5];
  const float* eemb = (const float*)d_in[6];
  const float* ew1  = (const float*)d_in[7];
  const float* eb1  = (const float*)d_in[8];
  const float* ew2  = (const float*)d_in[9];
  const float* eb2  = (const float*)d_in[10];
  float* out = (float*)d_out;

  char* ws = (char*)d_ws;
  const size_t W1T_BYTES = (size_t)E_ * H_ * D_ * 2;     // 16 MiB
  ushort* w1t    = (ushort*)ws;
  float*  pooled = (float*)(ws + W1T_BYTES);             // 256 KiB
  int*    ridx   = (int*)  (ws + W1T_BYTES + 262144);    // 512 B
  float*  rwgt   = (float*)(ws + W1T_BYTES + 262144 + 512);
  float*  ppart  = (float*)(ws + W1T_BYTES + 262144 + 1024);  // 4 MiB

  w1_transpose_kernel<<<dim3(16, 16, 8), 256, 0, stream>>>(ew1, w1t);
  pool_kernel<<<dim3(B_), 256, 0, stream>>>(x, emb, pooled);
  gate_kernel<<<dim3(B_), 256, 0, stream>>>(pooled, gw1, gb1, gw2, gb2, ridx, rwgt);
  expert_kernel<<<dim3(8, 8, NPAIR), 256, 0, stream>>>(x, eemb, w1t, eb1, ridx, ppart);
  finalize_kernel<<<dim3(B_), 256, 0, stream>>>(ppart, ridx, rwgt, ew2, eb2, out);
}

// Round 2
// 404.118 us; speedup vs baseline: 1.1136x; 1.1136x over previous
//
#include <hip/hip_runtime.h>
#include <hip/hip_bf16.h>

// Problem constants
#define V_   16000
#define D_   1024
#define H_   1024
#define E_   8
#define C_   16
#define B_   64
#define S_   512
#define GH_  256
#define NPAIR 128   // B_ * K(=2)

typedef short  bf16x8 __attribute__((ext_vector_type(8)));
typedef ushort u16x8  __attribute__((ext_vector_type(8)));
typedef float  f32x4  __attribute__((ext_vector_type(4)));

static __device__ __forceinline__ ushort f2bf(float f) {
  union { float f; unsigned u; } un; un.f = f;
  unsigned u = un.u;
  return (ushort)((u + 0x7FFFu + ((u >> 16) & 1u)) >> 16);  // RNE
}

static __device__ __forceinline__ unsigned pk2(float lo, float hi) {
  __hip_bfloat162 h = __float22bfloat162_rn(make_float2(lo, hi));  // v_cvt_pk_bf16_f32
  unsigned r; __builtin_memcpy(&r, &h, sizeof(r)); return r;
}

static __device__ __forceinline__ void gload_lds16(const void* g, void* l) {
  __builtin_amdgcn_global_load_lds((const __attribute__((address_space(1))) void*)g,
                                   (__attribute__((address_space(3))) void*)l, 16, 0, 0);
}

// ---------------------------------------------------------------------------
// Kernel 0: transpose+convert exp_w1 (E,D,H) f32 -> w1t, K-tiled + swizzled:
//   layout [e][hblk(4)][kb(16)][tile], tile = 256 h-rows x 64 k (bf16),
//   ushort idx within tile = hr*64 + (kc ^ ((hr&7)<<3))
// grid (16 kb, 16 ht, 8 e), block 256
__global__ void w1_transpose_kernel(const float* __restrict__ w1,
                                    ushort* __restrict__ w1t) {
  __shared__ float tile[64][65];
  const int kb = blockIdx.x, ht = blockIdx.y, e = blockIdx.z;
  const int d0 = kb * 64, h0 = ht * 64;
  const float* src = w1 + (size_t)e * D_ * H_;
  for (int i = threadIdx.x; i < 64 * 64; i += 256) {
    int r = i >> 6, c = i & 63;                 // r: d-local, c: h-local
    tile[r][c] = src[(size_t)(d0 + r) * H_ + h0 + c];
  }
  __syncthreads();
  const int hblk = ht >> 2;
  const int hrBase = (ht & 3) * 64;
  ushort* tbase = w1t + ((size_t)((e * 4 + hblk) * 16 + kb)) * (256 * 64);
  for (int i = threadIdx.x; i < 512; i += 256) {  // 64 h-rows x 8 k-groups
    int r = i >> 3, g = i & 7;
    int hr = hrBase + r;
    u16x8 v;
    #pragma unroll
    for (int j = 0; j < 8; ++j) v[j] = f2bf(tile[g * 8 + j][r]);
    int off = hr * 64 + ((g * 8) ^ ((hr & 7) << 3));
    *reinterpret_cast<u16x8*>(tbase + off) = v;
  }
}

// ---------------------------------------------------------------------------
// Kernel 1: partial pooling: partial[b][sb][d] = sum_{s in sb} emb[x[b,s]][d]
// grid (64, 8), block 256 (float4)
__global__ void pool_partial_kernel(const int* __restrict__ x,
                                    const float* __restrict__ emb,
                                    float* __restrict__ partial) {
  const int b = blockIdx.x, sb = blockIdx.y, t = threadIdx.x;
  const int* xr = x + b * S_ + sb * 64;
  float4 acc = make_float4(0.f, 0.f, 0.f, 0.f);
  #pragma unroll 4
  for (int s = 0; s < 64; ++s) {
    const float4* row = reinterpret_cast<const float4*>(emb + (size_t)xr[s] * D_);
    float4 v = row[t];
    acc.x += v.x; acc.y += v.y; acc.z += v.z; acc.w += v.w;
  }
  reinterpret_cast<float4*>(partial + ((size_t)b * 8 + sb) * D_)[t] = acc;
}

// ---------------------------------------------------------------------------
// Kernel 2: reduce partials + gating MLP + top-2 + renormalize (all f32)
// grid(64), block 256
__global__ void gate_kernel(const float* __restrict__ partial,
                            const float* __restrict__ gw1, const float* __restrict__ gb1,
                            const float* __restrict__ gw2, const float* __restrict__ gb2,
                            int* __restrict__ ridx, float* __restrict__ rwgt) {
  const int b = blockIdx.x, j = threadIdx.x;
  __shared__ float pl[D_];
  __shared__ float hid[GH_];
  __shared__ float logits[E_];
  for (int d = j; d < D_; d += 256) {
    float s = 0.f;
    #pragma unroll
    for (int sb = 0; sb < 8; ++sb) s += partial[((size_t)b * 8 + sb) * D_ + d];
    pl[d] = s * (1.f / (float)S_);
  }
  __syncthreads();
  float acc = gb1[j];
  for (int d = 0; d < D_; ++d) acc += pl[d] * gw1[d * GH_ + j];
  hid[j] = fmaxf(acc, 0.f);
  __syncthreads();
  if (j < E_) {
    float l = gb2[j];
    for (int i = 0; i < GH_; ++i) l += hid[i] * gw2[i * E_ + j];
    logits[j] = l;
  }
  __syncthreads();
  if (j == 0) {
    int i0 = 0; float v0 = logits[0];
    for (int i = 1; i < E_; ++i) if (logits[i] > v0) { v0 = logits[i]; i0 = i; }
    int i1 = -1; float v1 = -3.0e38f;
    for (int i = 0; i < E_; ++i) {
      if (i == i0) continue;
      if (logits[i] > v1) { v1 = logits[i]; i1 = i; }
    }
    float r1 = expf(v1 - v0);
    float norm = 1.f + r1;
    ridx[b * 2 + 0] = i0;         ridx[b * 2 + 1] = i1;
    rwgt[b * 2 + 0] = 1.f / norm; rwgt[b * 2 + 1] = r1 / norm;
  }
}

// ---------------------------------------------------------------------------
// Kernel 3: per-pair gathered GEMM + bias + ReLU + sum over s
// A = w1t (pre-swizzled tiles, global_load_lds, dbuf), B = gathered tokens
// (reg-staged f32->bf16, swizzled ds_write, dbuf). One barrier per K-step.
// block tile: BH=256 h x BS=64 s, BK=64; 4 waves, wave tile 64x64 (4x4 frags)
// grid (S/64=8, H/256=4, NPAIR=128)
#define BH 256
#define BS 64
#define BK 64

__global__ __launch_bounds__(256, 2) void expert_kernel(
    const int* __restrict__ x, const float* __restrict__ exp_emb,
    const ushort* __restrict__ w1t, const float* __restrict__ exp_b1,
    const int* __restrict__ ridx, float* __restrict__ p_part) {
  const int sblk = blockIdx.x;   // 0..7
  const int hblk = blockIdx.y;   // 0..3
  const int pr   = blockIdx.z;   // 0..127
  const int b    = pr >> 1;
  const int tid  = threadIdx.x;

  __shared__ __align__(16) ushort lA[2][BH * BK];   // 2 x 32 KiB
  __shared__ __align__(16) ushort lB[2][BS * BK];   // 2 x 8 KiB

  const int e     = ridx[pr];
  const int hBase = hblk * BH;
  const int sBase = sblk * BS;

  // A tile stream: [e][hblk][kb][256*64] pre-swizzled ushorts
  const ushort* aTile = w1t + ((size_t)((e * 4 + hblk) * 16)) * (BH * BK);

  // B gather: thread covers token row (tid>>2), floats [bq, bq+16)
  const int brow = tid >> 2, bq = (tid & 3) * 16;
  const int tok  = x[b * S_ + sBase + brow];
  const float* tokPtr = exp_emb + ((size_t)e * V_ + tok) * D_ + bq;

  const int wid = tid >> 6, lane = tid & 63;
  const int l15 = lane & 15, l16 = lane >> 4;
  const int wh  = wid * 64;                 // wave owns h rows [wh, wh+64)
  const int sw  = (l15 & 7) << 3;           // read-side swizzle (ushort units)
  const int ka0 = (l16 * 8) ^ sw;           // ks=0 column index
  const int ka1 = (32 + l16 * 8) ^ sw;      // ks=1 column index

  // B write offsets (swizzled ushort idx), 2 x 16B per thread
  const int bsw = (brow & 7) << 3;
  const int bw0 = brow * 64 + ((bq    ) ^ bsw);
  const int bw1 = brow * 64 + ((bq + 8) ^ bsw);

  f32x4 acc[4][4];
  #pragma unroll
  for (int i = 0; i < 4; ++i)
    #pragma unroll
    for (int j = 0; j < 4; ++j) acc[i][j] = (f32x4){0.f, 0.f, 0.f, 0.f};

  // ---- prologue: B(0) -> lB[0]; issue A(0); prefetch B(1) regs
  float4 f[4];
  {
    const float4* tp = reinterpret_cast<const float4*>(tokPtr);
    #pragma unroll
    for (int q = 0; q < 4; ++q) f[q] = tp[q];
    uint4 w0, w1v;
    w0.x = pk2(f[0].x, f[0].y); w0.y = pk2(f[0].z, f[0].w);
    w0.z = pk2(f[1].x, f[1].y); w0.w = pk2(f[1].z, f[1].w);
    w1v.x = pk2(f[2].x, f[2].y); w1v.y = pk2(f[2].z, f[2].w);
    w1v.z = pk2(f[3].x, f[3].y); w1v.w = pk2(f[3].z, f[3].w);
    *reinterpret_cast<uint4*>(&lB[0][bw0]) = w0;
    *reinterpret_cast<uint4*>(&lB[0][bw1]) = w1v;
  }
  {
    const char* src = reinterpret_cast<const char*>(aTile);
    #pragma unroll
    for (int i = 0; i < 8; ++i)
      gload_lds16(src + i * 4096 + tid * 16,
                  (char*)&lA[0][0] + i * 4096 + wid * 1024);
  }
  {
    const float4* tp = reinterpret_cast<const float4*>(tokPtr + 64);
    #pragma unroll
    for (int q = 0; q < 4; ++q) f[q] = tp[q];
  }
  __syncthreads();

  // ---- main loop: one barrier per K-step
  for (int kb = 0; kb < 16; ++kb) {
    const int cur = kb & 1, nxt = cur ^ 1;

    // issue A(kb+1) -> lA[nxt] (prev readers of lA[nxt] finished at last barrier)
    if (kb < 15) {
      const char* src = reinterpret_cast<const char*>(aTile + (size_t)(kb + 1) * (BH * BK));
      #pragma unroll
      for (int i = 0; i < 8; ++i)
        gload_lds16(src + i * 4096 + tid * 16,
                    (char*)&lA[nxt][0] + i * 4096 + wid * 1024);
    }

    // compute K-step kb
    const ushort* Ac = &lA[cur][0];
    const ushort* Bc = &lB[cur][0];
    #pragma unroll
    for (int ks = 0; ks < 2; ++ks) {
      const int ka = ks ? ka1 : ka0;
      bf16x8 af[4], bfr[4];
      #pragma unroll
      for (int i = 0; i < 4; ++i)
        af[i] = *reinterpret_cast<const bf16x8*>(&Ac[(wh + i * 16 + l15) * 64 + ka]);
      #pragma unroll
      for (int j = 0; j < 4; ++j)
        bfr[j] = *reinterpret_cast<const bf16x8*>(&Bc[(j * 16 + l15) * 64 + ka]);
      #pragma unroll
      for (int i = 0; i < 4; ++i)
        #pragma unroll
        for (int j = 0; j < 4; ++j)
          acc[i][j] = __builtin_amdgcn_mfma_f32_16x16x32_bf16(af[i], bfr[j], acc[i][j], 0, 0, 0);
    }

    // convert prefetched B(kb+1) -> lB[nxt]; then issue B(kb+2) loads
    if (kb < 15) {
      uint4 w0, w1v;
      w0.x = pk2(f[0].x, f[0].y); w0.y = pk2(f[0].z, f[0].w);
      w0.z = pk2(f[1].x, f[1].y); w0.w = pk2(f[1].z, f[1].w);
      w1v.x = pk2(f[2].x, f[2].y); w1v.y = pk2(f[2].z, f[2].w);
      w1v.z = pk2(f[3].x, f[3].y); w1v.w = pk2(f[3].z, f[3].w);
      *reinterpret_cast<uint4*>(&lB[nxt][bw0]) = w0;
      *reinterpret_cast<uint4*>(&lB[nxt][bw1]) = w1v;
      if (kb < 14) {
        const float4* tp = reinterpret_cast<const float4*>(tokPtr + (kb + 2) * 64);
        #pragma unroll
        for (int q = 0; q < 4; ++q) f[q] = tp[q];
      }
    }
    __syncthreads();
  }

  // ---- epilogue: + bias, ReLU, sum over 64 s columns, store partial
  float* outRow = p_part + (size_t)(sblk * NPAIR + pr) * H_ + hBase;
  const float* biasRow = exp_b1 + e * H_ + hBase;
  #pragma unroll
  for (int i = 0; i < 4; ++i) {
    #pragma unroll
    for (int r = 0; r < 4; ++r) {
      const int hloc = wh + i * 16 + l16 * 4 + r;   // D row = (lane>>4)*4 + reg
      const float bias = biasRow[hloc];
      float v = 0.f;
      #pragma unroll
      for (int j = 0; j < 4; ++j) v += fmaxf(acc[i][j][r] + bias, 0.f);
      #pragma unroll
      for (int m = 1; m < 16; m <<= 1) v += __shfl_xor(v, m);  // reduce 16 s-cols
      if (l15 == 0) outRow[hloc] = v;
    }
  }
}

// ---------------------------------------------------------------------------
// Kernel 4: out[b][c] = sum_k rw * ( (sum_sb p_part)/S @ W2[e] + b2[e] )
// grid(64), block 256: c = t&15, group g = t>>4
__global__ void finalize_kernel(const float* __restrict__ p_part,
                                const int* __restrict__ ridx, const float* __restrict__ rwgt,
                                const float* __restrict__ w2, const float* __restrict__ b2,
                                float* __restrict__ out) {
  const int b = blockIdx.x, t = threadIdx.x;
  const int c = t & 15, g = t >> 4;
  __shared__ float red[16][17];
  float res = 0.f;
  for (int kk = 0; kk < 2; ++kk) {
    const int pr = b * 2 + kk;
    const int e = ridx[pr];
    const float w = rwgt[pr];
    float dot = 0.f;
    for (int h = g; h < H_; h += 16) {
      float pm = 0.f;
      #pragma unroll
      for (int sb = 0; sb < 8; ++sb) pm += p_part[(size_t)(sb * NPAIR + pr) * H_ + h];
      dot += pm * w2[((size_t)e * H_ + h) * C_ + c];
    }
    red[g][c] = dot;
    __syncthreads();
    if (g == 0) {
      float s = 0.f;
      #pragma unroll
      for (int i = 0; i < 16; ++i) s += red[i][c];
      res += w * (s * (1.f / (float)S_) + b2[e * C_ + c]);
    }
    __syncthreads();
  }
  if (g == 0) out[b * C_ + c] = res;
}

// ---------------------------------------------------------------------------
extern "C" void kernel_launch(void* const* d_in, const int* in_sizes, int n_in,
                              void* d_out, int out_size, void* d_ws, size_t ws_size,
                              hipStream_t stream) {
  const int*   x    = (const int*)  d_in[0];
  const float* emb  = (const float*)d_in[1];
  const float* gw1  = (const float*)d_in[2];
  const float* gb1  = (const float*)d_in[3];
  const float* gw2  = (const float*)d_in[4];
  const float* gb2  = (const float*)d_in[5];
  const float* eemb = (const float*)d_in[6];
  const float* ew1  = (const float*)d_in[7];
  const float* eb1  = (const float*)d_in[8];
  const float* ew2  = (const float*)d_in[9];
  const float* eb2  = (const float*)d_in[10];
  float* out = (float*)d_out;

  char* ws = (char*)d_ws;
  const size_t OFF_W1T   = 0;                            // 16 MiB
  const size_t OFF_PART  = (size_t)16 << 20;             // 2 MiB
  const size_t OFF_RIDX  = OFF_PART + ((size_t)2 << 20);
  const size_t OFF_RWGT  = OFF_RIDX + 1024;
  const size_t OFF_PPART = OFF_RWGT + 1024;              // 4 MiB

  ushort* w1t    = (ushort*)(ws + OFF_W1T);
  float*  part   = (float*) (ws + OFF_PART);
  int*    ridx   = (int*)   (ws + OFF_RIDX);
  float*  rwgt   = (float*) (ws + OFF_RWGT);
  float*  ppart  = (float*) (ws + OFF_PPART);

  w1_transpose_kernel<<<dim3(16, 16, 8), 256, 0, stream>>>(ew1, w1t);
  pool_partial_kernel<<<dim3(B_, 8), 256, 0, stream>>>(x, emb, part);
  gate_kernel<<<dim3(B_), 256, 0, stream>>>(part, gw1, gb1, gw2, gb2, ridx, rwgt);
  expert_kernel<<<dim3(8, 4, NPAIR), 256, 0, stream>>>(x, eemb, w1t, eb1, ridx, ppart);
  finalize_kernel<<<dim3(B_), 256, 0, stream>>>(ppart, ridx, rwgt, ew2, eb2, out);
}

// Round 3
// 366.070 us; speedup vs baseline: 1.2293x; 1.1039x over previous
//
#include <hip/hip_runtime.h>
#include <hip/hip_bf16.h>

// Problem constants
#define V_   16000
#define D_   1024
#define H_   1024
#define E_   8
#define C_   16
#define B_   64
#define S_   512
#define GH_  256
#define NPAIR 128   // B_ * K(=2)

typedef short  bf16x8 __attribute__((ext_vector_type(8)));
typedef ushort u16x8  __attribute__((ext_vector_type(8)));
typedef float  f32x4  __attribute__((ext_vector_type(4)));

static __device__ __forceinline__ ushort f2bf(float f) {
  union { float f; unsigned u; } un; un.f = f;
  unsigned u = un.u;
  return (ushort)((u + 0x7FFFu + ((u >> 16) & 1u)) >> 16);  // RNE
}

static __device__ __forceinline__ unsigned pk2(float lo, float hi) {
  __hip_bfloat162 h = __float22bfloat162_rn(make_float2(lo, hi));  // v_cvt_pk_bf16_f32
  unsigned r; __builtin_memcpy(&r, &h, sizeof(r)); return r;
}

// ---------------------------------------------------------------------------
// Kernel 0: repack exp_w1 (E,D,H) f32 -> w1t bf16 in MFMA-fragment order:
//   ushort offset = ((e*32 + kk)*64 + ht)*512 + lane*8 + j
//   holds A[h = ht*16 + (lane&15)][k = kk*32 + (lane>>4)*8 + j]
// grid (16 dtile, 16 htile, 8 e), block 256
__global__ void w1_transpose_kernel(const float* __restrict__ w1,
                                    ushort* __restrict__ w1t) {
  __shared__ float tile[64][65];
  const int dtile = blockIdx.x, htile = blockIdx.y, e = blockIdx.z;
  const int d0 = dtile * 64, h0 = htile * 64;
  const float* src = w1 + (size_t)e * D_ * H_;
  for (int i = threadIdx.x; i < 64 * 64; i += 256) {
    int r = i >> 6, c = i & 63;                 // r: d-local, c: h-local
    tile[r][c] = src[(size_t)(d0 + r) * H_ + h0 + c];
  }
  __syncthreads();
  // 8 chunks: kkl in [0,2), htl in [0,4); each chunk = 64 lanes x u16x8
  for (int i = threadIdx.x; i < 512; i += 256) {
    int chunk = i >> 6, lane = i & 63;
    int kkl = chunk >> 2, htl = chunk & 3;
    int l15 = lane & 15, l16 = lane >> 4;
    u16x8 v;
    #pragma unroll
    for (int j = 0; j < 8; ++j)
      v[j] = f2bf(tile[kkl * 32 + l16 * 8 + j][htl * 16 + l15]);
    size_t off = ((size_t)((e * 32 + dtile * 2 + kkl) * 64 + htile * 4 + htl)) * 512 + lane * 8;
    *reinterpret_cast<u16x8*>(w1t + off) = v;
  }
}

// ---------------------------------------------------------------------------
// Kernel 1: partial pooling: partial[b][sb][d] = sum_{s in sb} emb[x[b,s]][d]
// grid (64, 8), block 256 (float4)
__global__ void pool_partial_kernel(const int* __restrict__ x,
                                    const float* __restrict__ emb,
                                    float* __restrict__ partial) {
  const int b = blockIdx.x, sb = blockIdx.y, t = threadIdx.x;
  const int* xr = x + b * S_ + sb * 64;
  float4 acc = make_float4(0.f, 0.f, 0.f, 0.f);
  #pragma unroll 4
  for (int s = 0; s < 64; ++s) {
    const float4* row = reinterpret_cast<const float4*>(emb + (size_t)xr[s] * D_);
    float4 v = row[t];
    acc.x += v.x; acc.y += v.y; acc.z += v.z; acc.w += v.w;
  }
  reinterpret_cast<float4*>(partial + ((size_t)b * 8 + sb) * D_)[t] = acc;
}

// ---------------------------------------------------------------------------
// Kernel 2: reduce partials + gating MLP + top-2 + renormalize (all f32)
// grid(64), block 256
__global__ void gate_kernel(const float* __restrict__ partial,
                            const float* __restrict__ gw1, const float* __restrict__ gb1,
                            const float* __restrict__ gw2, const float* __restrict__ gb2,
                            int* __restrict__ ridx, float* __restrict__ rwgt) {
  const int b = blockIdx.x, j = threadIdx.x;
  __shared__ float pl[D_];
  __shared__ float hid[GH_];
  __shared__ float logits[E_];
  for (int d = j; d < D_; d += 256) {
    float s = 0.f;
    #pragma unroll
    for (int sb = 0; sb < 8; ++sb) s += partial[((size_t)b * 8 + sb) * D_ + d];
    pl[d] = s * (1.f / (float)S_);
  }
  __syncthreads();
  float acc = gb1[j];
  for (int d = 0; d < D_; ++d) acc += pl[d] * gw1[d * GH_ + j];
  hid[j] = fmaxf(acc, 0.f);
  __syncthreads();
  if (j < E_) {
    float l = gb2[j];
    for (int i = 0; i < GH_; ++i) l += hid[i] * gw2[i * E_ + j];
    logits[j] = l;
  }
  __syncthreads();
  if (j == 0) {
    int i0 = 0; float v0 = logits[0];
    for (int i = 1; i < E_; ++i) if (logits[i] > v0) { v0 = logits[i]; i0 = i; }
    int i1 = -1; float v1 = -3.0e38f;
    for (int i = 0; i < E_; ++i) {
      if (i == i0) continue;
      if (logits[i] > v1) { v1 = logits[i]; i1 = i; }
    }
    float r1 = expf(v1 - v0);
    float norm = 1.f + r1;
    ridx[b * 2 + 0] = i0;         ridx[b * 2 + 1] = i1;
    rwgt[b * 2 + 0] = 1.f / norm; rwgt[b * 2 + 1] = r1 / norm;
  }
}

// ---------------------------------------------------------------------------
// Kernel 3: token-stationary gathered GEMM + bias + ReLU + sum over s
//   Block owns 64 tokens (s) x ALL H=1024, K=1024. Token tile (64x1024 bf16,
//   swizzled) lives in LDS, gathered ONCE (slab-pipelined under h-iter 0).
//   A (w1t) is pre-packed in fragment order -> loaded global->VGPR directly.
//   h-iter 1 has no barriers and no LDS writes.
// grid (128 pr, 8 sblk), block 512 (8 waves, wave tile 64h x 64s)
__global__ __launch_bounds__(512, 2) void expert_kernel(
    const int* __restrict__ x, const float* __restrict__ exp_emb,
    const ushort* __restrict__ w1t, const float* __restrict__ exp_b1,
    const int* __restrict__ ridx, float* __restrict__ p_part) {
  const int pr   = blockIdx.x;   // 0..127  (pr%8 -> XCD: 8 sblk blocks share XCD)
  const int sblk = blockIdx.y;   // 0..7
  const int b    = pr >> 1;
  const int tid  = threadIdx.x;

  __shared__ __align__(16) ushort lB[64 * 1024];   // 128 KiB token tile

  const int e = ridx[pr];

  // gather mapping: thread covers token row (tid>>3), 8 floats at (tid&7)*8
  const int grow = tid >> 3, gkq = (tid & 7) * 8;
  const int tok  = x[b * S_ + sblk * 64 + grow];
  const float* gptr = exp_emb + ((size_t)e * V_ + tok) * D_ + gkq;
  const int gdst = grow * 1024 + (gkq ^ ((grow & 7) << 3));  // + slab*64

  const int wid = tid >> 6, lane = tid & 63;
  const int l15 = lane & 15, l16 = lane >> 4;
  const int sw  = (l15 & 7) << 3;

  const ushort* aLane = w1t + (size_t)e * (32 * 64 * 512) + lane * 8;

  f32x4 acc[4][4];
  #pragma unroll
  for (int i = 0; i < 4; ++i)
    #pragma unroll
    for (int j = 0; j < 4; ++j) acc[i][j] = (f32x4){0.f, 0.f, 0.f, 0.f};

  // ---- preload + write slab 0
  float4 c0 = *reinterpret_cast<const float4*>(gptr);
  float4 c1 = *reinterpret_cast<const float4*>(gptr + 4);
  {
    uint4 w;
    w.x = pk2(c0.x, c0.y); w.y = pk2(c0.z, c0.w);
    w.z = pk2(c1.x, c1.y); w.w = pk2(c1.z, c1.w);
    *reinterpret_cast<uint4*>(&lB[gdst]) = w;
  }

  // ---- h-iter 0 with slab-pipelined gather (16 barriers total)
  #pragma unroll
  for (int slab = 0; slab < 16; ++slab) {
    __syncthreads();                       // slab is visible
    float4 n0, n1;
    if (slab < 15) {                       // issue next slab's loads NOW;
      n0 = *reinterpret_cast<const float4*>(gptr + (slab + 1) * 64);
      n1 = *reinterpret_cast<const float4*>(gptr + (slab + 1) * 64 + 4);
    }
    // compute 2 K-steps (kk) of h-iter 0 on this slab
    #pragma unroll
    for (int ks = 0; ks < 2; ++ks) {
      const int kk = slab * 2 + ks;
      const int colk = (kk >> 1) * 64 + ((((kk & 1) << 5) | (l16 << 3)) ^ sw);
      bf16x8 bfr[4], af[4];
      #pragma unroll
      for (int j = 0; j < 4; ++j)
        bfr[j] = *reinterpret_cast<const bf16x8*>(&lB[(j * 16 + l15) * 1024 + colk]);
      #pragma unroll
      for (int i = 0; i < 4; ++i)
        af[i] = *reinterpret_cast<const bf16x8*>(aLane + ((size_t)kk * 64 + wid * 4 + i) * 512);
      #pragma unroll
      for (int i = 0; i < 4; ++i)
        #pragma unroll
        for (int j = 0; j < 4; ++j)
          acc[i][j] = __builtin_amdgcn_mfma_f32_16x16x32_bf16(af[i], bfr[j], acc[i][j], 0, 0, 0);
    }
    // convert + write next slab (loads had the MFMA section to land)
    if (slab < 15) {
      uint4 w;
      w.x = pk2(n0.x, n0.y); w.y = pk2(n0.z, n0.w);
      w.z = pk2(n1.x, n1.y); w.w = pk2(n1.z, n1.w);
      *reinterpret_cast<uint4*>(&lB[gdst + (slab + 1) * 64]) = w;
    }
  }

  // ---- epilogue h-iter 0 (h in [0,512))
  float* outRow = p_part + (size_t)(sblk * NPAIR + pr) * H_;
  const float* biasE = exp_b1 + e * H_;
  #pragma unroll
  for (int i = 0; i < 4; ++i) {
    #pragma unroll
    for (int r = 0; r < 4; ++r) {
      const int h = wid * 64 + i * 16 + l16 * 4 + r;
      const float bias = biasE[h];
      float v = 0.f;
      #pragma unroll
      for (int j = 0; j < 4; ++j) v += fmaxf(acc[i][j][r] + bias, 0.f);
      #pragma unroll
      for (int m = 1; m < 16; m <<= 1) v += __shfl_xor(v, m);
      if (l15 == 0) outRow[h] = v;
      acc[i][0][r] = 0.f;  // re-zero while we're here
    }
    #pragma unroll
    for (int j = 1; j < 4; ++j) acc[i][j] = (f32x4){0.f, 0.f, 0.f, 0.f};
  }

  // ---- h-iter 1: barrier-free, LDS-write-free (h in [512,1024))
  #pragma unroll 4
  for (int kk = 0; kk < 32; ++kk) {
    const int colk = (kk >> 1) * 64 + ((((kk & 1) << 5) | (l16 << 3)) ^ sw);
    bf16x8 bfr[4], af[4];
    #pragma unroll
    for (int j = 0; j < 4; ++j)
      bfr[j] = *reinterpret_cast<const bf16x8*>(&lB[(j * 16 + l15) * 1024 + colk]);
    #pragma unroll
    for (int i = 0; i < 4; ++i)
      af[i] = *reinterpret_cast<const bf16x8*>(aLane + ((size_t)kk * 64 + 32 + wid * 4 + i) * 512);
    #pragma unroll
    for (int i = 0; i < 4; ++i)
      #pragma unroll
      for (int j = 0; j < 4; ++j)
        acc[i][j] = __builtin_amdgcn_mfma_f32_16x16x32_bf16(af[i], bfr[j], acc[i][j], 0, 0, 0);
  }

  // ---- epilogue h-iter 1
  #pragma unroll
  for (int i = 0; i < 4; ++i) {
    #pragma unroll
    for (int r = 0; r < 4; ++r) {
      const int h = 512 + wid * 64 + i * 16 + l16 * 4 + r;
      const float bias = biasE[h];
      float v = 0.f;
      #pragma unroll
      for (int j = 0; j < 4; ++j) v += fmaxf(acc[i][j][r] + bias, 0.f);
      #pragma unroll
      for (int m = 1; m < 16; m <<= 1) v += __shfl_xor(v, m);
      if (l15 == 0) outRow[h] = v;
    }
  }
}

// ---------------------------------------------------------------------------
// Kernel 4: out[b][c] = sum_k rw * ( (sum_sb p_part)/S @ W2[e] + b2[e] )
// grid(64), block 256: c = t&15, group g = t>>4
__global__ void finalize_kernel(const float* __restrict__ p_part,
                                const int* __restrict__ ridx, const float* __restrict__ rwgt,
                                const float* __restrict__ w2, const float* __restrict__ b2,
                                float* __restrict__ out) {
  const int b = blockIdx.x, t = threadIdx.x;
  const int c = t & 15, g = t >> 4;
  __shared__ float red[16][17];
  float res = 0.f;
  for (int kk = 0; kk < 2; ++kk) {
    const int pr = b * 2 + kk;
    const int e = ridx[pr];
    const float w = rwgt[pr];
    float dot = 0.f;
    for (int h = g; h < H_; h += 16) {
      float pm = 0.f;
      #pragma unroll
      for (int sb = 0; sb < 8; ++sb) pm += p_part[(size_t)(sb * NPAIR + pr) * H_ + h];
      dot += pm * w2[((size_t)e * H_ + h) * C_ + c];
    }
    red[g][c] = dot;
    __syncthreads();
    if (g == 0) {
      float s = 0.f;
      #pragma unroll
      for (int i = 0; i < 16; ++i) s += red[i][c];
      res += w * (s * (1.f / (float)S_) + b2[e * C_ + c]);
    }
    __syncthreads();
  }
  if (g == 0) out[b * C_ + c] = res;
}

// ---------------------------------------------------------------------------
extern "C" void kernel_launch(void* const* d_in, const int* in_sizes, int n_in,
                              void* d_out, int out_size, void* d_ws, size_t ws_size,
                              hipStream_t stream) {
  const int*   x    = (const int*)  d_in[0];
  const float* emb  = (const float*)d_in[1];
  const float* gw1  = (const float*)d_in[2];
  const float* gb1  = (const float*)d_in[3];
  const float* gw2  = (const float*)d_in[4];
  const float* gb2  = (const float*)d_in[5];
  const float* eemb = (const float*)d_in[6];
  const float* ew1  = (const float*)d_in[7];
  const float* eb1  = (const float*)d_in[8];
  const float* ew2  = (const float*)d_in[9];
  const float* eb2  = (const float*)d_in[10];
  float* out = (float*)d_out;

  char* ws = (char*)d_ws;
  const size_t OFF_W1T   = 0;                            // 16 MiB
  const size_t OFF_PART  = (size_t)16 << 20;             // 2 MiB
  const size_t OFF_RIDX  = OFF_PART + ((size_t)2 << 20);
  const size_t OFF_RWGT  = OFF_RIDX + 1024;
  const size_t OFF_PPART = OFF_RWGT + 1024;              // 4 MiB

  ushort* w1t    = (ushort*)(ws + OFF_W1T);
  float*  part   = (float*) (ws + OFF_PART);
  int*    ridx   = (int*)   (ws + OFF_RIDX);
  float*  rwgt   = (float*) (ws + OFF_RWGT);
  float*  ppart  = (float*) (ws + OFF_PPART);

  w1_transpose_kernel<<<dim3(16, 16, 8), 256, 0, stream>>>(ew1, w1t);
  pool_partial_kernel<<<dim3(B_, 8), 256, 0, stream>>>(x, emb, part);
  gate_kernel<<<dim3(B_), 256, 0, stream>>>(part, gw1, gb1, gw2, gb2, ridx, rwgt);
  expert_kernel<<<dim3(128, 8), 512, 0, stream>>>(x, eemb, w1t, eb1, ridx, ppart);
  finalize_kernel<<<dim3(B_), 256, 0, stream>>>(ppart, ridx, rwgt, ew2, eb2, out);
}

// Round 4
// 301.590 us; speedup vs baseline: 1.4921x; 1.2138x over previous
//
#include <hip/hip_runtime.h>
#include <hip/hip_bf16.h>

// Problem constants
#define V_   16000
#define D_   1024
#define H_   1024
#define E_   8
#define C_   16
#define B_   64
#define S_   512
#define GH_  256
#define NPAIR 128   // B_ * K(=2)

typedef short  bf16x8 __attribute__((ext_vector_type(8)));
typedef ushort u16x8  __attribute__((ext_vector_type(8)));
typedef float  f32x4  __attribute__((ext_vector_type(4)));

static __device__ __forceinline__ ushort f2bf(float f) {
  union { float f; unsigned u; } un; un.f = f;
  unsigned u = un.u;
  return (ushort)((u + 0x7FFFu + ((u >> 16) & 1u)) >> 16);  // RNE
}

static __device__ __forceinline__ unsigned pk2(float lo, float hi) {
  __hip_bfloat162 h = __float22bfloat162_rn(make_float2(lo, hi));  // v_cvt_pk_bf16_f32
  unsigned r; __builtin_memcpy(&r, &h, sizeof(r)); return r;
}

// ---------------------------------------------------------------------------
// Kernel 0 (fused prep):
//  blocks [0,2048): repack exp_w1 (E,D,H) f32 -> w1t bf16, MFMA-fragment order:
//     ushort offset = ((e*32 + kk)*64 + ht)*512 + lane*8 + j
//     holds A[h = ht*16 + (lane&15)][k = kk*32 + (lane>>4)*8 + j]
//  blocks [2048,2560): partial pooling partial[b][sb][d] = sum_{s in sb} emb[x[b,s]][d]
__global__ void prep_kernel(const float* __restrict__ w1, ushort* __restrict__ w1t,
                            const int* __restrict__ x, const float* __restrict__ emb,
                            float* __restrict__ partial) {
  __shared__ float tile[64][65];
  const int id = blockIdx.x;
  if (id < 2048) {
    const int e = id >> 8, rem = id & 255;
    const int dtile = rem & 15, htile = rem >> 4;
    const int d0 = dtile * 64, h0 = htile * 64;
    const float* src = w1 + (size_t)e * D_ * H_;
    for (int i = threadIdx.x; i < 64 * 64; i += 256) {
      int r = i >> 6, c = i & 63;                 // r: d-local, c: h-local
      tile[r][c] = src[(size_t)(d0 + r) * H_ + h0 + c];
    }
    __syncthreads();
    for (int i = threadIdx.x; i < 512; i += 256) {
      int chunk = i >> 6, lane = i & 63;
      int kkl = chunk >> 2, htl = chunk & 3;
      int l15 = lane & 15, l16 = lane >> 4;
      u16x8 v;
      #pragma unroll
      for (int j = 0; j < 8; ++j)
        v[j] = f2bf(tile[kkl * 32 + l16 * 8 + j][htl * 16 + l15]);
      size_t off = ((size_t)((e * 32 + dtile * 2 + kkl) * 64 + htile * 4 + htl)) * 512 + lane * 8;
      *reinterpret_cast<u16x8*>(w1t + off) = v;
    }
  } else {
    const int pid = id - 2048;
    const int b = pid >> 3, sb = pid & 7, t = threadIdx.x;
    const int* xr = x + b * S_ + sb * 64;
    float4 acc = make_float4(0.f, 0.f, 0.f, 0.f);
    #pragma unroll 4
    for (int s = 0; s < 64; ++s) {
      const float4* row = reinterpret_cast<const float4*>(emb + (size_t)xr[s] * D_);
      float4 v = row[t];
      acc.x += v.x; acc.y += v.y; acc.z += v.z; acc.w += v.w;
    }
    reinterpret_cast<float4*>(partial + ((size_t)b * 8 + sb) * D_)[t] = acc;
  }
}

// ---------------------------------------------------------------------------
// Kernel 1: reduce partials + gating MLP + top-2 + renormalize (all f32)
// grid(64), block 256
__global__ void gate_kernel(const float* __restrict__ partial,
                            const float* __restrict__ gw1, const float* __restrict__ gb1,
                            const float* __restrict__ gw2, const float* __restrict__ gb2,
                            int* __restrict__ ridx, float* __restrict__ rwgt) {
  const int b = blockIdx.x, j = threadIdx.x;
  __shared__ float pl[D_];
  __shared__ float hid[GH_];
  __shared__ float logits[E_];
  for (int d = j; d < D_; d += 256) {
    float s = 0.f;
    #pragma unroll
    for (int sb = 0; sb < 8; ++sb) s += partial[((size_t)b * 8 + sb) * D_ + d];
    pl[d] = s * (1.f / (float)S_);
  }
  __syncthreads();
  float acc = gb1[j];
  for (int d = 0; d < D_; ++d) acc += pl[d] * gw1[d * GH_ + j];
  hid[j] = fmaxf(acc, 0.f);
  __syncthreads();
  if (j < E_) {
    float l = gb2[j];
    for (int i = 0; i < GH_; ++i) l += hid[i] * gw2[i * E_ + j];
    logits[j] = l;
  }
  __syncthreads();
  if (j == 0) {
    int i0 = 0; float v0 = logits[0];
    for (int i = 1; i < E_; ++i) if (logits[i] > v0) { v0 = logits[i]; i0 = i; }
    int i1 = -1; float v1 = -3.0e38f;
    for (int i = 0; i < E_; ++i) {
      if (i == i0) continue;
      if (logits[i] > v1) { v1 = logits[i]; i1 = i; }
    }
    float r1 = expf(v1 - v0);
    float norm = 1.f + r1;
    ridx[b * 2 + 0] = i0;         ridx[b * 2 + 1] = i1;
    rwgt[b * 2 + 0] = 1.f / norm; rwgt[b * 2 + 1] = r1 / norm;
  }
}

// ---------------------------------------------------------------------------
// Kernel 2: stable counting-rank sort of pairs by expert id. 1 block, 128 thr.
__global__ void sort_pairs_kernel(const int* __restrict__ ridx, int* __restrict__ order) {
  __shared__ int se[NPAIR];
  const int t = threadIdx.x;
  se[t] = ridx[t];
  __syncthreads();
  const int e = se[t];
  int rank = 0;
  for (int j = 0; j < NPAIR; ++j) {
    const int ej = se[j];
    rank += (ej < e || (ej == e && j < t)) ? 1 : 0;
  }
  order[rank] = t;
}

// ---------------------------------------------------------------------------
// Kernel 3: token-stationary gathered GEMM + bias + ReLU + sum over s
//   Block owns 64 tokens (s) x ALL H=1024, K=1024. Token tile (64x1024 bf16,
//   swizzled) in LDS, gathered ONCE (slab-pipelined under h-iter 0, NT loads).
//   A (w1t) pre-packed in fragment order, global->VGPR with 1-deep prefetch.
//   Pairs sorted by expert + XCD-chunked mapping -> w1t slab (2 MiB) L2-hits.
// grid(1024), block 512 (8 waves, wave tile 64h x 64s)
__global__ __launch_bounds__(512, 2) void expert_kernel(
    const int* __restrict__ x, const float* __restrict__ exp_emb,
    const ushort* __restrict__ w1t, const float* __restrict__ exp_b1,
    const int* __restrict__ ridx, const int* __restrict__ order,
    float* __restrict__ p_part) {
  const int id     = blockIdx.x;           // 0..1023
  const int xcd    = id & 7;
  const int within = id >> 3;              // 0..127
  const int slot   = xcd * 128 + within;   // contiguous sorted chunk per XCD
  const int pr     = order[slot >> 3];
  const int sblk   = slot & 7;
  const int b      = pr >> 1;
  const int tid    = threadIdx.x;

  __shared__ __align__(16) ushort lB[64 * 1024];   // 128 KiB token tile

  const int e = ridx[pr];

  // gather mapping: thread covers token row (tid>>3), 8 floats at (tid&7)*8
  const int grow = tid >> 3, gkq = (tid & 7) * 8;
  const int tok  = x[b * S_ + sblk * 64 + grow];
  const float* gptr = exp_emb + ((size_t)e * V_ + tok) * D_ + gkq;
  const int gdst = grow * 1024 + (gkq ^ ((grow & 7) << 3));  // + slab*64

  const int wid = tid >> 6, lane = tid & 63;
  const int l15 = lane & 15, l16 = lane >> 4;
  const int sw  = (l15 & 7) << 3;

  // A fragment stream base for this wave/lane
  const ushort* aW = w1t + (size_t)e * (32 * 64 * 512) + ((size_t)wid * 4) * 512 + (size_t)lane * 8;
  // t in [0,64): kk = t&31, ht-add = (t>>5)*32; fragment i in [0,4)
  #define LOADA(t_, i_) \
    (*reinterpret_cast<const bf16x8*>(aW + ((size_t)(((t_) & 31) * 64 + ((t_) >> 5) * 32 + (i_))) * 512))

  f32x4 acc[4][4];
  #pragma unroll
  for (int i = 0; i < 4; ++i)
    #pragma unroll
    for (int j = 0; j < 4; ++j) acc[i][j] = (f32x4){0.f, 0.f, 0.f, 0.f};

  // ---- preload + write slab 0
  {
    f32x4 c0 = __builtin_nontemporal_load(reinterpret_cast<const f32x4*>(gptr));
    f32x4 c1 = __builtin_nontemporal_load(reinterpret_cast<const f32x4*>(gptr + 4));
    uint4 w;
    w.x = pk2(c0[0], c0[1]); w.y = pk2(c0[2], c0[3]);
    w.z = pk2(c1[0], c1[1]); w.w = pk2(c1[2], c1[3]);
    *reinterpret_cast<uint4*>(&lB[gdst]) = w;
  }

  bf16x8 af[4];
  #pragma unroll
  for (int i = 0; i < 4; ++i) af[i] = LOADA(0, i);

  // ---- h-iter 0 with slab-pipelined gather (16 barriers total)
  #pragma unroll
  for (int slab = 0; slab < 16; ++slab) {
    __syncthreads();                       // slab is visible
    f32x4 n0, n1;
    if (slab < 15) {                       // issue next slab's loads NOW
      n0 = __builtin_nontemporal_load(reinterpret_cast<const f32x4*>(gptr + (slab + 1) * 64));
      n1 = __builtin_nontemporal_load(reinterpret_cast<const f32x4*>(gptr + (slab + 1) * 64 + 4));
    }
    #pragma unroll
    for (int ks = 0; ks < 2; ++ks) {
      const int kk = slab * 2 + ks;
      bf16x8 afn[4];
      #pragma unroll
      for (int i = 0; i < 4; ++i) afn[i] = LOADA(kk + 1, i);   // kk+1 <= 32 (crosses into h-iter1)
      const int colk = (kk >> 1) * 64 + ((((kk & 1) << 5) | (l16 << 3)) ^ sw);
      bf16x8 bfr[4];
      #pragma unroll
      for (int j = 0; j < 4; ++j)
        bfr[j] = *reinterpret_cast<const bf16x8*>(&lB[(j * 16 + l15) * 1024 + colk]);
      #pragma unroll
      for (int i = 0; i < 4; ++i)
        #pragma unroll
        for (int j = 0; j < 4; ++j)
          acc[i][j] = __builtin_amdgcn_mfma_f32_16x16x32_bf16(af[i], bfr[j], acc[i][j], 0, 0, 0);
      #pragma unroll
      for (int i = 0; i < 4; ++i) af[i] = afn[i];
    }
    // convert + write next slab (loads had the MFMA section to land)
    if (slab < 15) {
      uint4 w;
      w.x = pk2(n0[0], n0[1]); w.y = pk2(n0[2], n0[3]);
      w.z = pk2(n1[0], n1[1]); w.w = pk2(n1[2], n1[3]);
      *reinterpret_cast<uint4*>(&lB[gdst + (slab + 1) * 64]) = w;
    }
  }

  // ---- epilogue h-iter 0 (h in [0,512))
  float* outRow = p_part + (size_t)(sblk * NPAIR + pr) * H_;
  const float* biasE = exp_b1 + e * H_;
  #pragma unroll
  for (int i = 0; i < 4; ++i) {
    #pragma unroll
    for (int r = 0; r < 4; ++r) {
      const int h = wid * 64 + i * 16 + l16 * 4 + r;
      const float bias = biasE[h];
      float v = 0.f;
      #pragma unroll
      for (int j = 0; j < 4; ++j) v += fmaxf(acc[i][j][r] + bias, 0.f);
      #pragma unroll
      for (int m = 1; m < 16; m <<= 1) v += __shfl_xor(v, m);
      if (l15 == 0) outRow[h] = v;
      acc[i][0][r] = 0.f;  // re-zero while we're here
    }
    #pragma unroll
    for (int j = 1; j < 4; ++j) acc[i][j] = (f32x4){0.f, 0.f, 0.f, 0.f};
  }

  // ---- h-iter 1: barrier-free, LDS-write-free (h in [512,1024))
  #pragma unroll 4
  for (int t2 = 32; t2 < 64; ++t2) {
    bf16x8 afn[4];
    if (t2 < 63) {
      #pragma unroll
      for (int i = 0; i < 4; ++i) afn[i] = LOADA(t2 + 1, i);
    }
    const int kk = t2 - 32;
    const int colk = (kk >> 1) * 64 + ((((kk & 1) << 5) | (l16 << 3)) ^ sw);
    bf16x8 bfr[4];
    #pragma unroll
    for (int j = 0; j < 4; ++j)
      bfr[j] = *reinterpret_cast<const bf16x8*>(&lB[(j * 16 + l15) * 1024 + colk]);
    #pragma unroll
    for (int i = 0; i < 4; ++i)
      #pragma unroll
      for (int j = 0; j < 4; ++j)
        acc[i][j] = __builtin_amdgcn_mfma_f32_16x16x32_bf16(af[i], bfr[j], acc[i][j], 0, 0, 0);
    #pragma unroll
    for (int i = 0; i < 4; ++i) af[i] = afn[i];
  }

  // ---- epilogue h-iter 1
  #pragma unroll
  for (int i = 0; i < 4; ++i) {
    #pragma unroll
    for (int r = 0; r < 4; ++r) {
      const int h = 512 + wid * 64 + i * 16 + l16 * 4 + r;
      const float bias = biasE[h];
      float v = 0.f;
      #pragma unroll
      for (int j = 0; j < 4; ++j) v += fmaxf(acc[i][j][r] + bias, 0.f);
      #pragma unroll
      for (int m = 1; m < 16; m <<= 1) v += __shfl_xor(v, m);
      if (l15 == 0) outRow[h] = v;
    }
  }
  #undef LOADA
}

// ---------------------------------------------------------------------------
// Kernel 4: out[b][c] = sum_k rw * ( (sum_sb p_part)/S @ W2[e] + b2[e] )
// grid(64), block 256: c = t&15, group g = t>>4
__global__ void finalize_kernel(const float* __restrict__ p_part,
                                const int* __restrict__ ridx, const float* __restrict__ rwgt,
                                const float* __restrict__ w2, const float* __restrict__ b2,
                                float* __restrict__ out) {
  const int b = blockIdx.x, t = threadIdx.x;
  const int c = t & 15, g = t >> 4;
  __shared__ float red[16][17];
  float res = 0.f;
  for (int kk = 0; kk < 2; ++kk) {
    const int pr = b * 2 + kk;
    const int e = ridx[pr];
    const float w = rwgt[pr];
    float dot = 0.f;
    for (int h = g; h < H_; h += 16) {
      float pm = 0.f;
      #pragma unroll
      for (int sb = 0; sb < 8; ++sb) pm += p_part[(size_t)(sb * NPAIR + pr) * H_ + h];
      dot += pm * w2[((size_t)e * H_ + h) * C_ + c];
    }
    red[g][c] = dot;
    __syncthreads();
    if (g == 0) {
      float s = 0.f;
      #pragma unroll
      for (int i = 0; i < 16; ++i) s += red[i][c];
      res += w * (s * (1.f / (float)S_) + b2[e * C_ + c]);
    }
    __syncthreads();
  }
  if (g == 0) out[b * C_ + c] = res;
}

// ---------------------------------------------------------------------------
extern "C" void kernel_launch(void* const* d_in, const int* in_sizes, int n_in,
                              void* d_out, int out_size, void* d_ws, size_t ws_size,
                              hipStream_t stream) {
  const int*   x    = (const int*)  d_in[0];
  const float* emb  = (const float*)d_in[1];
  const float* gw1  = (const float*)d_in[2];
  const float* gb1  = (const float*)d_in[3];
  const float* gw2  = (const float*)d_in[4];
  const float* gb2  = (const float*)d_in[5];
  const float* eemb = (const float*)d_in[6];
  const float* ew1  = (const float*)d_in[7];
  const float* eb1  = (const float*)d_in[8];
  const float* ew2  = (const float*)d_in[9];
  const float* eb2  = (const float*)d_in[10];
  float* out = (float*)d_out;

  char* ws = (char*)d_ws;
  const size_t OFF_W1T   = 0;                            // 16 MiB
  const size_t OFF_PART  = (size_t)16 << 20;             // 2 MiB
  const size_t OFF_RIDX  = OFF_PART + ((size_t)2 << 20);
  const size_t OFF_RWGT  = OFF_RIDX + 1024;
  const size_t OFF_ORDER = OFF_RWGT + 1024;
  const size_t OFF_PPART = OFF_ORDER + 1024;             // 4 MiB

  ushort* w1t    = (ushort*)(ws + OFF_W1T);
  float*  part   = (float*) (ws + OFF_PART);
  int*    ridx   = (int*)   (ws + OFF_RIDX);
  float*  rwgt   = (float*) (ws + OFF_RWGT);
  int*    order  = (int*)   (ws + OFF_ORDER);
  float*  ppart  = (float*) (ws + OFF_PPART);

  prep_kernel<<<dim3(2560), 256, 0, stream>>>(ew1, w1t, x, emb, part);
  gate_kernel<<<dim3(B_), 256, 0, stream>>>(part, gw1, gb1, gw2, gb2, ridx, rwgt);
  sort_pairs_kernel<<<dim3(1), 128, 0, stream>>>(ridx, order);
  expert_kernel<<<dim3(1024), 512, 0, stream>>>(x, eemb, w1t, eb1, ridx, order, ppart);
  finalize_kernel<<<dim3(B_), 256, 0, stream>>>(ppart, ridx, rwgt, ew2, eb2, out);
}